// Round 13
// baseline (200.315 us; speedup 1.0000x reference)
//
#include <hip/hip_runtime.h>

#define TPB 256
#define BSH 5                    // 32 dst nodes per bucket
#define BNODES 32
#define CAP 1024                 // slots per bucket region (mean load 512)
#define EPB 4096                 // edges per partition block
#define NBMAX 3200               // LDS counter array bound (nb = 3125)

// ---------------- deterministic bucket partition (counting sort) ------------

// pass 1: per-block bucket histogram via LDS int atomics; clean row write
__global__ void k_hist1(const int* __restrict__ dst, int* __restrict__ hist,
                        int nb, int E) {
    __shared__ int sh[NBMAX];
    int tid = threadIdx.x, blk = blockIdx.x;
    for (int i = tid; i < nb; i += TPB) sh[i] = 0;
    __syncthreads();
    int e0 = blk * EPB;
    for (int i = tid; i < EPB; i += TPB) {
        int e = e0 + i;
        if (e < E) atomicAdd(&sh[dst[e] >> BSH], 1);
    }
    __syncthreads();
    int* hrow = hist + (size_t)blk * nb;
    for (int i = tid; i < nb; i += TPB) hrow[i] = sh[i];
}

// pass 2: per-bucket slot offsets in STRIPE-GROUPED block order
__global__ void k_scanoff(const int* __restrict__ hist, int* __restrict__ offs,
                          int* __restrict__ bcnt, int nblk, int nb) {
    int t = blockIdx.x * TPB + threadIdx.x;
    int b = t >> 3, s = t & 7;
    if (b >= nb) return;
    int nps = (nblk + 7) >> 3;
    int sum = 0;
    for (int q = 0; q < nps; ++q) {
        int blk = q * 8 + s;
        if (blk < nblk) sum += hist[(size_t)blk * nb + b];
    }
    int v = sum;
#pragma unroll
    for (int o = 1; o < 8; o <<= 1) {
        int u = __shfl_up(v, o, 8);
        if (s >= o) v += u;
    }
    int total = __shfl(v, 7, 8);
    if (s == 0) bcnt[b] = total;
    int off = b * CAP + (v - sum);   // exclusive within bucket, stripe-grouped
    for (int q = 0; q < nps; ++q) {
        int blk = q * 8 + s;
        if (blk < nblk) {
            offs[(size_t)blk * nb + b] = off;
            off += hist[(size_t)blk * nb + b];
        }
    }
}

// pass 3: scatter edges to exact slots; LDS cursors, ZERO global atomics
__global__ void k_scatter(const int* __restrict__ src, const int* __restrict__ dst,
                          const int* __restrict__ offs, unsigned* __restrict__ ebuf,
                          int nb, int E) {
    __shared__ int cur[NBMAX];
    int tid = threadIdx.x, blk = blockIdx.x;
    const int* orow = offs + (size_t)blk * nb;
    for (int i = tid; i < nb; i += TPB) cur[i] = orow[i];
    __syncthreads();
    int e0 = blk * EPB;
    for (int i = tid; i < EPB; i += TPB) {
        int e = e0 + i;
        if (e < E) {
            int d = dst[e];
            int pos = atomicAdd(&cur[d >> BSH], 1);   // int LDS atomic: native
            ebuf[pos] = ((unsigned)src[e] << BSH) | (unsigned)(d & (BNODES - 1));
        }
    }
}

// one WAVE per bucket: stage edges, int-LDS histogram, shfl-scan,
// scatter into padded per-node CSR; emit deg / node_beg / dinv.
__global__ void k_bcsr(const int* __restrict__ bcnt, const unsigned* __restrict__ ebuf,
                       int* __restrict__ csr, int* __restrict__ node_beg,
                       int* __restrict__ degi, float* __restrict__ dinv, int nb, int n) {
    __shared__ unsigned se[4][CAP];        // 16 KB edge stage
    __shared__ int scnt[4][BNODES];
    __shared__ int sexc[4][BNODES];
    __shared__ int srnk[4][BNODES];
    int wv = threadIdx.x >> 6, lane = threadIdx.x & 63;
    int b = blockIdx.x * 4 + wv;
    bool act = (b < nb);
    if (lane < BNODES) { scnt[wv][lane] = 0; srnk[wv][lane] = 0; }
    __syncthreads();
    int cnt = 0;
    if (act) {
        cnt = bcnt[b];
        if (cnt > CAP) cnt = CAP;
        const unsigned* p = &ebuf[(size_t)b * CAP];
        for (int k = lane; k < cnt; k += 64) {
            unsigned pk = p[k];
            se[wv][k] = pk;
            atomicAdd(&scnt[wv][pk & (BNODES - 1)], 1);   // int LDS atomic
        }
    }
    __syncthreads();
    if (act && lane < BNODES) {
        int dg = scnt[wv][lane];
        int v = dg;
#pragma unroll
        for (int off = 1; off < BNODES; off <<= 1) {
            int t = __shfl_up(v, off, BNODES);
            if (lane >= off) v += t;
        }
        int excl = v - dg;
        sexc[wv][lane] = excl;
        int node = b * BNODES + lane;
        if (node < n) {
            degi[node] = dg;
            node_beg[node] = b * CAP + excl;
            dinv[node] = rsqrtf((float)dg + 1.0f);
        }
    }
    __syncthreads();
    if (act) {
        int* csrb = csr + (size_t)b * CAP;
        for (int k = lane; k < cnt; k += 64) {
            unsigned pk = se[wv][k];
            int dl = pk & (BNODES - 1);
            int r = atomicAdd(&srnk[wv][dl], 1);
            csrb[sexc[wv][dl] + r] = (int)(pk >> BSH);
        }
    }
}

// ---------------- dense transform layer 1 (register-blocked tile GEMM) ------

// g[row,:] = fp16(dinv[row]*(x[row,:]@W1)); 64 rows/block, 4x4 acc per thread
__global__ void k_xw64v(const float* __restrict__ x, const float* __restrict__ W,
                        const float* __restrict__ dinv, _Float16* __restrict__ g, int n) {
    __shared__ float Ws[64 * 64];    // [k][c]
    __shared__ float xsT[64 * 64];   // [k][row_local]
    int tid = threadIdx.x;
    int row0 = blockIdx.x * 64;
    for (int i = tid; i < 1024; i += TPB)
        reinterpret_cast<float4*>(Ws)[i] = reinterpret_cast<const float4*>(W)[i];
    {
        int rl = tid >> 2, cq = (tid & 3) * 16;
        int row = row0 + rl;
#pragma unroll
        for (int j4 = 0; j4 < 4; ++j4) {
            float4 v = make_float4(0.f, 0.f, 0.f, 0.f);
            if (row < n) v = *reinterpret_cast<const float4*>(x + (size_t)row * 64 + cq + j4 * 4);
            xsT[(cq + j4 * 4 + 0) * 64 + rl] = v.x;
            xsT[(cq + j4 * 4 + 1) * 64 + rl] = v.y;
            xsT[(cq + j4 * 4 + 2) * 64 + rl] = v.z;
            xsT[(cq + j4 * 4 + 3) * 64 + rl] = v.w;
        }
    }
    __syncthreads();
    int c4 = (tid & 15) * 4, rq = (tid >> 4) * 4;
    float acc[4][4] = {};
#pragma unroll 4
    for (int k = 0; k < 64; ++k) {
        float4 wv = *reinterpret_cast<const float4*>(Ws + k * 64 + c4);
        float4 xv = *reinterpret_cast<const float4*>(xsT + k * 64 + rq);
        const float* wp = (const float*)&wv;
        const float* xp = (const float*)&xv;
#pragma unroll
        for (int i = 0; i < 4; ++i)
#pragma unroll
            for (int j = 0; j < 4; ++j) acc[i][j] += xp[i] * wp[j];
    }
#pragma unroll
    for (int i = 0; i < 4; ++i) {
        int row = row0 + rq + i;
        if (row < n) {
            float dv = dinv[row];
            _Float16 o[4];
#pragma unroll
            for (int j = 0; j < 4; ++j) o[j] = (_Float16)(dv * acc[i][j]);
            *reinterpret_cast<ushort4*>(g + (size_t)row * 64 + c4) =
                *reinterpret_cast<const ushort4*>(o);
        }
    }
}

// ---------------- FUSED layer-1 gather + relu + layer-2 transform -----------

// One wave per node. Gather loop: lane=(eidx<<3)|fch, 4 predicated uint4
// loads per lane per iter (32 edges in flight). After the xor-reduce tree,
// EVERY lane holds the full acc[8] for its chunk fch, so the whole h row
// (fp32, pre-fp16-rounding) lives in-wave: compute h = relu(dv*agg+b1),
// then g2 = fp16(dv * (h @ W2)) via 24 FMAs/lane + fch-axis xor reduce.
// h never touches memory (saves 25 MB of traffic + one kernel).
__global__ void k_g64f(const int* __restrict__ node_beg, const int* __restrict__ degi,
                       const int* __restrict__ csr, const float* __restrict__ dinv,
                       const _Float16* __restrict__ g, const float* __restrict__ b1,
                       const float* __restrict__ W2, _Float16* __restrict__ g2, int n) {
    __shared__ float W2s[64 * 19];   // [k][c]
    __shared__ float b1s[64];
    int tid = threadIdx.x;
    for (int i = tid; i < 64 * 19; i += TPB) W2s[i] = W2[i];
    if (tid < 64) b1s[tid] = b1[tid];
    __syncthreads();

    int node = blockIdx.x * 4 + (tid >> 6);
    if (node >= n) return;
    int lane = tid & 63;
    int eidx = lane >> 3, fch = lane & 7;   // 8 edge slots x 8 chunks(8 fp16)
    int beg = node_beg[node], cnt = degi[node];
    const uint4* gb = (const uint4*)g;      // 8 uint4 per 64-col row
    float acc[8];
#pragma unroll
    for (int j = 0; j < 8; ++j) acc[j] = 0.f;
    for (int base = 0; base < cnt; base += 32) {
        int k0 = base + eidx, k1 = base + 8 + eidx;
        int k2 = base + 16 + eidx, k3 = base + 24 + eidx;
        bool v0 = (k0 < cnt), v1 = (k1 < cnt), v2 = (k2 < cnt), v3 = (k3 < cnt);
        int r0 = v0 ? csr[beg + k0] : 0;
        int r1 = v1 ? csr[beg + k1] : 0;
        int r2 = v2 ? csr[beg + k2] : 0;
        int r3 = v3 ? csr[beg + k3] : 0;
        uint4 A = v0 ? gb[(size_t)r0 * 8 + fch] : make_uint4(0, 0, 0, 0);
        uint4 B = v1 ? gb[(size_t)r1 * 8 + fch] : make_uint4(0, 0, 0, 0);
        uint4 C = v2 ? gb[(size_t)r2 * 8 + fch] : make_uint4(0, 0, 0, 0);
        uint4 D = v3 ? gb[(size_t)r3 * 8 + fch] : make_uint4(0, 0, 0, 0);
        const _Float16* fa = (const _Float16*)&A;
        const _Float16* fb = (const _Float16*)&B;
        const _Float16* fc = (const _Float16*)&C;
        const _Float16* fd = (const _Float16*)&D;
#pragma unroll
        for (int j = 0; j < 8; ++j)
            acc[j] += ((float)fa[j] + (float)fb[j]) + ((float)fc[j] + (float)fd[j]);
    }
#pragma unroll
    for (int m = 8; m < 64; m <<= 1) {
#pragma unroll
        for (int j = 0; j < 8; ++j) acc[j] += __shfl_xor(acc[j], m);
    }
    // every lane: full h chunk fch in fp32
    uint4 sv = gb[(size_t)node * 8 + fch];          // self-loop row chunk
    const _Float16* sf = (const _Float16*)&sv;
    float dv = dinv[node];
    float hv[8];
#pragma unroll
    for (int j = 0; j < 8; ++j)
        hv[j] = fmaxf(dv * (acc[j] + (float)sf[j]) + b1s[fch * 8 + j], 0.f);
    // partial dots: lane (eidx,fch) covers cols c = eidx + 8m over k-range fch*8..+7
    float p0 = 0.f, p1 = 0.f, p2 = 0.f;
    {
        int c0 = eidx, c1 = eidx + 8, c2 = eidx + 16;
#pragma unroll
        for (int j = 0; j < 8; ++j) {
            float hj = hv[j];
            const float* wrow = W2s + (fch * 8 + j) * 19;
            p0 += hj * wrow[c0];
            p1 += hj * wrow[c1];
            if (c2 < 19) p2 += hj * wrow[c2];
        }
    }
#pragma unroll
    for (int m = 1; m < 8; m <<= 1) {
        p0 += __shfl_xor(p0, m);
        p1 += __shfl_xor(p1, m);
        p2 += __shfl_xor(p2, m);
    }
    if (fch == 0) {
        g2[(size_t)node * 19 + eidx] = (_Float16)(dv * p0);
        g2[(size_t)node * 19 + eidx + 8] = (_Float16)(dv * p1);
        if (eidx + 16 < 19) g2[(size_t)node * 19 + eidx + 16] = (_Float16)(dv * p2);
    }
}

// unpadded [N][19] gather: 2 nodes/wave, lane&31 = col (19 active), 8-unroll
__global__ void k_gath19(const int* __restrict__ node_beg, const int* __restrict__ degi,
                         const int* __restrict__ csr, const float* __restrict__ dinv,
                         const _Float16* __restrict__ g2, const float* __restrict__ b2,
                         float* __restrict__ out, int n) {
    int node = blockIdx.x * 8 + (threadIdx.x >> 5);
    if (node >= n) return;
    int c = threadIdx.x & 31;
    if (c >= 19) return;
    int beg = node_beg[node], cnt = degi[node];
    float a0 = (float)g2[(size_t)node * 19 + c];     // self-loop
    float a1 = 0.f, a2 = 0.f, a3 = 0.f;
    float a4 = 0.f, a5 = 0.f, a6 = 0.f, a7 = 0.f;
    int k = 0;
    for (; k + 7 < cnt; k += 8) {
        int s0 = csr[beg + k];
        int s1 = csr[beg + k + 1];
        int s2 = csr[beg + k + 2];
        int s3 = csr[beg + k + 3];
        int s4 = csr[beg + k + 4];
        int s5 = csr[beg + k + 5];
        int s6 = csr[beg + k + 6];
        int s7 = csr[beg + k + 7];
        a0 += (float)g2[(size_t)s0 * 19 + c];
        a1 += (float)g2[(size_t)s1 * 19 + c];
        a2 += (float)g2[(size_t)s2 * 19 + c];
        a3 += (float)g2[(size_t)s3 * 19 + c];
        a4 += (float)g2[(size_t)s4 * 19 + c];
        a5 += (float)g2[(size_t)s5 * 19 + c];
        a6 += (float)g2[(size_t)s6 * 19 + c];
        a7 += (float)g2[(size_t)s7 * 19 + c];
    }
    for (; k < cnt; ++k) a1 += (float)g2[(size_t)csr[beg + k] * 19 + c];
    float s = ((a0 + a1) + (a2 + a3)) + ((a4 + a5) + (a6 + a7));
    out[(size_t)node * 19 + c] = dinv[node] * s + b2[c];
}

// ---------------- launch ----------------

extern "C" void kernel_launch(void* const* d_in, const int* in_sizes, int n_in,
                              void* d_out, int out_size, void* d_ws, size_t ws_size,
                              hipStream_t stream) {
    const float* x  = (const float*)d_in[0];
    const int*   ei = (const int*)d_in[1];
    const float* W1 = (const float*)d_in[2];
    const float* b1 = (const float*)d_in[3];
    const float* W2 = (const float*)d_in[4];
    const float* b2 = (const float*)d_in[5];
    float* out = (float*)d_out;

    int N = in_sizes[0] / 64;
    int E = in_sizes[1] / 2;
    const int* src = ei;
    const int* dst = ei + E;

    int NB = (N + BNODES - 1) >> BSH;        // 3125 for N=100000
    int NBLK = (E + EPB - 1) / EPB;          // 391 for E=1.6M

    char* w = (char*)d_ws;
    int* bcnt      = (int*)w;      w += (size_t)NB * 4;
    int* degi      = (int*)w;      w += (size_t)N * 4;
    int* node_beg  = (int*)w;      w += (size_t)N * 4;
    float* dinv    = (float*)w;    w += (size_t)N * 4;
    w = (char*)(((size_t)w + 63) & ~(size_t)63);
    // region A: hist+offs (build passes), later reused as csr (bcsr onward)
    char* regionA  = w;
    size_t histB   = (size_t)NBLK * NB * 4;                  // 4.9 MB
    size_t csrB    = (size_t)NB * CAP * 4;                   // 12.8 MB
    size_t regA    = (histB * 2 > csrB) ? histB * 2 : csrB;
    int* hist      = (int*)regionA;
    int* offs      = (int*)(regionA + histB);
    int* csr       = (int*)regionA;          // alias: hist/offs dead by k_bcsr
    w += regA;
    unsigned* ebuf = (unsigned*)w; w += (size_t)NB * CAP * 4;
    _Float16* g1   = (_Float16*)w; w += (size_t)N * 64 * 2;
    _Float16* g2   = (_Float16*)w; w += (size_t)N * 19 * 2;  // distinct from g1
                                                             // (g64f reads g1
                                                             // while writing g2)

    k_hist1   <<<NBLK, TPB, 0, stream>>>(dst, hist, NB, E);
    k_scanoff <<<(NB * 8 + TPB - 1) / TPB, TPB, 0, stream>>>(hist, offs, bcnt, NBLK, NB);
    k_scatter <<<NBLK, TPB, 0, stream>>>(src, dst, offs, ebuf, NB, E);
    k_bcsr    <<<(NB + 3) / 4, TPB, 0, stream>>>(bcnt, ebuf, csr, node_beg, degi, dinv, NB, N);

    k_xw64v   <<<(N + 63) / 64, TPB, 0, stream>>>(x, W1, dinv, g1, N);
    k_g64f    <<<(N + 3) / 4, TPB, 0, stream>>>(node_beg, degi, csr, dinv, g1, b1, W2, g2, N);
    k_gath19  <<<(N + 7) / 8, TPB, 0, stream>>>(node_beg, degi, csr, dinv, g2, b2, out, N);
}

// Round 14
// 187.938 us; speedup vs baseline: 1.0659x; 1.0659x over previous
//
#include <hip/hip_runtime.h>

#define TPB 256
#define BSH 5                    // 32 dst nodes per bucket
#define BNODES 32
#define CAP 1024                 // slots per bucket region (mean load 512)
#define EPB 8192                 // edges per partition block
#define NBMAX 3200               // LDS counter array bound (nb = 3125)

// ---------------- deterministic bucket partition (counting sort) ------------

// pass 1: per-block bucket histogram via LDS int atomics; clean row write
__global__ void k_hist1(const int* __restrict__ dst, int* __restrict__ hist,
                        int nb, int E) {
    __shared__ int sh[NBMAX];
    int tid = threadIdx.x, blk = blockIdx.x;
    for (int i = tid; i < nb; i += TPB) sh[i] = 0;
    __syncthreads();
    int e0 = blk * EPB;
    for (int i = tid; i < EPB; i += TPB) {
        int e = e0 + i;
        if (e < E) atomicAdd(&sh[dst[e] >> BSH], 1);
    }
    __syncthreads();
    int* hrow = hist + (size_t)blk * nb;
    for (int i = tid; i < nb; i += TPB) hrow[i] = sh[i];
}

// pass 2: per-bucket slot offsets in STRIPE-GROUPED block order
__global__ void k_scanoff(const int* __restrict__ hist, int* __restrict__ offs,
                          int* __restrict__ bcnt, int nblk, int nb) {
    int t = blockIdx.x * TPB + threadIdx.x;
    int b = t >> 3, s = t & 7;
    if (b >= nb) return;
    int nps = (nblk + 7) >> 3;
    int sum = 0;
    for (int q = 0; q < nps; ++q) {
        int blk = q * 8 + s;
        if (blk < nblk) sum += hist[(size_t)blk * nb + b];
    }
    int v = sum;
#pragma unroll
    for (int o = 1; o < 8; o <<= 1) {
        int u = __shfl_up(v, o, 8);
        if (s >= o) v += u;
    }
    int total = __shfl(v, 7, 8);
    if (s == 0) bcnt[b] = total;
    int off = b * CAP + (v - sum);   // exclusive within bucket, stripe-grouped
    for (int q = 0; q < nps; ++q) {
        int blk = q * 8 + s;
        if (blk < nblk) {
            offs[(size_t)blk * nb + b] = off;
            off += hist[(size_t)blk * nb + b];
        }
    }
}

// pass 3: scatter edges to exact slots; LDS cursors, ZERO global atomics
__global__ void k_scatter(const int* __restrict__ src, const int* __restrict__ dst,
                          const int* __restrict__ offs, unsigned* __restrict__ ebuf,
                          int nb, int E) {
    __shared__ int cur[NBMAX];
    int tid = threadIdx.x, blk = blockIdx.x;
    const int* orow = offs + (size_t)blk * nb;
    for (int i = tid; i < nb; i += TPB) cur[i] = orow[i];
    __syncthreads();
    int e0 = blk * EPB;
    for (int i = tid; i < EPB; i += TPB) {
        int e = e0 + i;
        if (e < E) {
            int d = dst[e];
            int pos = atomicAdd(&cur[d >> BSH], 1);   // int LDS atomic: native
            ebuf[pos] = ((unsigned)src[e] << BSH) | (unsigned)(d & (BNODES - 1));
        }
    }
}

// one WAVE per bucket: stage edges, int-LDS histogram, shfl-scan,
// scatter into padded per-node CSR; emit deg / node_beg / dinv.
__global__ void k_bcsr(const int* __restrict__ bcnt, const unsigned* __restrict__ ebuf,
                       int* __restrict__ csr, int* __restrict__ node_beg,
                       int* __restrict__ degi, float* __restrict__ dinv, int nb, int n) {
    __shared__ unsigned se[4][CAP];        // 16 KB edge stage
    __shared__ int scnt[4][BNODES];
    __shared__ int sexc[4][BNODES];
    __shared__ int srnk[4][BNODES];
    int wv = threadIdx.x >> 6, lane = threadIdx.x & 63;
    int b = blockIdx.x * 4 + wv;
    bool act = (b < nb);
    if (lane < BNODES) { scnt[wv][lane] = 0; srnk[wv][lane] = 0; }
    __syncthreads();
    int cnt = 0;
    if (act) {
        cnt = bcnt[b];
        if (cnt > CAP) cnt = CAP;
        const unsigned* p = &ebuf[(size_t)b * CAP];
        for (int k = lane; k < cnt; k += 64) {
            unsigned pk = p[k];
            se[wv][k] = pk;
            atomicAdd(&scnt[wv][pk & (BNODES - 1)], 1);   // int LDS atomic
        }
    }
    __syncthreads();
    if (act && lane < BNODES) {
        int dg = scnt[wv][lane];
        int v = dg;
#pragma unroll
        for (int off = 1; off < BNODES; off <<= 1) {
            int t = __shfl_up(v, off, BNODES);
            if (lane >= off) v += t;
        }
        int excl = v - dg;
        sexc[wv][lane] = excl;
        int node = b * BNODES + lane;
        if (node < n) {
            degi[node] = dg;
            node_beg[node] = b * CAP + excl;
            dinv[node] = rsqrtf((float)dg + 1.0f);
        }
    }
    __syncthreads();
    if (act) {
        int* csrb = csr + (size_t)b * CAP;
        for (int k = lane; k < cnt; k += 64) {
            unsigned pk = se[wv][k];
            int dl = pk & (BNODES - 1);
            int r = atomicAdd(&srnk[wv][dl], 1);
            csrb[sexc[wv][dl] + r] = (int)(pk >> BSH);
        }
    }
}

// ---------------- dense transforms (register-blocked tile GEMM) -------------

// g[row,:] = fp16(dinv[row]*(x[row,:]@W1)); 64 rows/block, 4x4 acc per thread
__global__ void k_xw64v(const float* __restrict__ x, const float* __restrict__ W,
                        const float* __restrict__ dinv, _Float16* __restrict__ g, int n) {
    __shared__ float Ws[64 * 64];    // [k][c]
    __shared__ float xsT[64 * 64];   // [k][row_local]
    int tid = threadIdx.x;
    int row0 = blockIdx.x * 64;
    for (int i = tid; i < 1024; i += TPB)
        reinterpret_cast<float4*>(Ws)[i] = reinterpret_cast<const float4*>(W)[i];
    {
        int rl = tid >> 2, cq = (tid & 3) * 16;
        int row = row0 + rl;
#pragma unroll
        for (int j4 = 0; j4 < 4; ++j4) {
            float4 v = make_float4(0.f, 0.f, 0.f, 0.f);
            if (row < n) v = *reinterpret_cast<const float4*>(x + (size_t)row * 64 + cq + j4 * 4);
            xsT[(cq + j4 * 4 + 0) * 64 + rl] = v.x;
            xsT[(cq + j4 * 4 + 1) * 64 + rl] = v.y;
            xsT[(cq + j4 * 4 + 2) * 64 + rl] = v.z;
            xsT[(cq + j4 * 4 + 3) * 64 + rl] = v.w;
        }
    }
    __syncthreads();
    int c4 = (tid & 15) * 4, rq = (tid >> 4) * 4;
    float acc[4][4] = {};
#pragma unroll 4
    for (int k = 0; k < 64; ++k) {
        float4 wv = *reinterpret_cast<const float4*>(Ws + k * 64 + c4);
        float4 xv = *reinterpret_cast<const float4*>(xsT + k * 64 + rq);
        const float* wp = (const float*)&wv;
        const float* xp = (const float*)&xv;
#pragma unroll
        for (int i = 0; i < 4; ++i)
#pragma unroll
            for (int j = 0; j < 4; ++j) acc[i][j] += xp[i] * wp[j];
    }
#pragma unroll
    for (int i = 0; i < 4; ++i) {
        int row = row0 + rq + i;
        if (row < n) {
            float dv = dinv[row];
            _Float16 o[4];
#pragma unroll
            for (int j = 0; j < 4; ++j) o[j] = (_Float16)(dv * acc[i][j]);
            *reinterpret_cast<ushort4*>(g + (size_t)row * 64 + c4) =
                *reinterpret_cast<const ushort4*>(o);
        }
    }
}

// g2[row,0:19] = fp16(dinv[row]*(h[row,:]@W2)) UNPADDED [N][19] (3.8 MB,
// near-L2-resident for the gather); 32 rows/block, 4 rows/thread
__global__ void k_xw19v(const _Float16* __restrict__ h, const float* __restrict__ W,
                        const float* __restrict__ dinv, _Float16* __restrict__ g2, int n) {
    __shared__ float Ws[64 * 32];    // [k][c], c>=19 zero
    __shared__ float xsT[64 * 32];   // [k][row_local]
    int tid = threadIdx.x;
    int row0 = blockIdx.x * 32;
    for (int i = tid; i < 64 * 32; i += TPB) {
        int k = i >> 5, c = i & 31;
        Ws[i] = (c < 19) ? W[k * 19 + c] : 0.f;
    }
    {
        int rl = tid >> 3, sq = tid & 7;
        int row = row0 + rl;
        if (row < n) {
            uint4 v = *(reinterpret_cast<const uint4*>(h + (size_t)row * 64) + sq);
            const _Float16* f = (const _Float16*)&v;
#pragma unroll
            for (int j = 0; j < 8; ++j) xsT[(sq * 8 + j) * 32 + rl] = (float)f[j];
        } else {
#pragma unroll
            for (int j = 0; j < 8; ++j) xsT[(sq * 8 + j) * 32 + rl] = 0.f;
        }
    }
    __syncthreads();
    int c = tid & 31, rg = (tid >> 5) * 4;
    float acc[4] = {};
#pragma unroll 4
    for (int k = 0; k < 64; ++k) {
        float wv = Ws[k * 32 + c];
        float4 xv = *reinterpret_cast<const float4*>(xsT + k * 32 + rg);
        const float* xp = (const float*)&xv;
#pragma unroll
        for (int i = 0; i < 4; ++i) acc[i] += xp[i] * wv;
    }
    if (c < 19) {
#pragma unroll
        for (int i = 0; i < 4; ++i) {
            int row = row0 + rg + i;
            if (row < n) g2[(size_t)row * 19 + c] = (_Float16)(dinv[row] * acc[i]);
        }
    }
}

// ---------------- gather aggregation (register accumulate, no atomics) ------

// full-row gather, 32 edges in flight: one wave per node, lane =
// (edge-slot<<3)|chunk, 4 INDEPENDENT predicated uint4 loads per lane per
// iteration. Single pass keeps the ~88 MB per-XCD-compulsory fetch floor;
// deep concurrency targets the ~2 TB/s random-line fabric rate.
__global__ void k_gath64d(const int* __restrict__ node_beg, const int* __restrict__ degi,
                          const int* __restrict__ csr, const float* __restrict__ dinv,
                          const _Float16* __restrict__ g, const float* __restrict__ b1,
                          _Float16* __restrict__ h, int n) {
    int node = blockIdx.x * 4 + (threadIdx.x >> 6);
    if (node >= n) return;
    int lane = threadIdx.x & 63;
    int eidx = lane >> 3, fch = lane & 7;   // 8 edge slots x 8 chunks(8 fp16)
    int beg = node_beg[node], cnt = degi[node];
    const uint4* gb = (const uint4*)g;      // 8 uint4 per 64-col row
    float acc[8];
#pragma unroll
    for (int j = 0; j < 8; ++j) acc[j] = 0.f;
    for (int base = 0; base < cnt; base += 32) {
        int k0 = base + eidx, k1 = base + 8 + eidx;
        int k2 = base + 16 + eidx, k3 = base + 24 + eidx;
        bool v0 = (k0 < cnt), v1 = (k1 < cnt), v2 = (k2 < cnt), v3 = (k3 < cnt);
        int r0 = v0 ? csr[beg + k0] : 0;
        int r1 = v1 ? csr[beg + k1] : 0;
        int r2 = v2 ? csr[beg + k2] : 0;
        int r3 = v3 ? csr[beg + k3] : 0;
        uint4 A = v0 ? gb[(size_t)r0 * 8 + fch] : make_uint4(0, 0, 0, 0);
        uint4 B = v1 ? gb[(size_t)r1 * 8 + fch] : make_uint4(0, 0, 0, 0);
        uint4 C = v2 ? gb[(size_t)r2 * 8 + fch] : make_uint4(0, 0, 0, 0);
        uint4 D = v3 ? gb[(size_t)r3 * 8 + fch] : make_uint4(0, 0, 0, 0);
        const _Float16* fa = (const _Float16*)&A;
        const _Float16* fb = (const _Float16*)&B;
        const _Float16* fc = (const _Float16*)&C;
        const _Float16* fd = (const _Float16*)&D;
#pragma unroll
        for (int j = 0; j < 8; ++j)
            acc[j] += ((float)fa[j] + (float)fb[j]) + ((float)fc[j] + (float)fd[j]);
    }
#pragma unroll
    for (int m = 8; m < 64; m <<= 1) {
#pragma unroll
        for (int j = 0; j < 8; ++j) acc[j] += __shfl_xor(acc[j], m);
    }
    if (eidx == 0) {   // lanes 0-7 hold chunks 0-7
        uint4 v = gb[(size_t)node * 8 + fch];       // self-loop
        const _Float16* f = (const _Float16*)&v;
        float dv = dinv[node];
        _Float16 outv[8];
#pragma unroll
        for (int j = 0; j < 8; ++j) {
            float val = dv * (acc[j] + (float)f[j]) + b1[fch * 8 + j];
            outv[j] = (_Float16)fmaxf(val, 0.f);
        }
        *((uint4*)(h + (size_t)node * 64) + fch) = *(const uint4*)outv;
    }
}

// unpadded [N][19] gather: 2 nodes/wave, lane&31 = col (19 active), 8-unroll
__global__ void k_gath19(const int* __restrict__ node_beg, const int* __restrict__ degi,
                         const int* __restrict__ csr, const float* __restrict__ dinv,
                         const _Float16* __restrict__ g2, const float* __restrict__ b2,
                         float* __restrict__ out, int n) {
    int node = blockIdx.x * 8 + (threadIdx.x >> 5);
    if (node >= n) return;
    int c = threadIdx.x & 31;
    if (c >= 19) return;
    int beg = node_beg[node], cnt = degi[node];
    float a0 = (float)g2[(size_t)node * 19 + c];     // self-loop
    float a1 = 0.f, a2 = 0.f, a3 = 0.f;
    float a4 = 0.f, a5 = 0.f, a6 = 0.f, a7 = 0.f;
    int k = 0;
    for (; k + 7 < cnt; k += 8) {
        int s0 = csr[beg + k];
        int s1 = csr[beg + k + 1];
        int s2 = csr[beg + k + 2];
        int s3 = csr[beg + k + 3];
        int s4 = csr[beg + k + 4];
        int s5 = csr[beg + k + 5];
        int s6 = csr[beg + k + 6];
        int s7 = csr[beg + k + 7];
        a0 += (float)g2[(size_t)s0 * 19 + c];
        a1 += (float)g2[(size_t)s1 * 19 + c];
        a2 += (float)g2[(size_t)s2 * 19 + c];
        a3 += (float)g2[(size_t)s3 * 19 + c];
        a4 += (float)g2[(size_t)s4 * 19 + c];
        a5 += (float)g2[(size_t)s5 * 19 + c];
        a6 += (float)g2[(size_t)s6 * 19 + c];
        a7 += (float)g2[(size_t)s7 * 19 + c];
    }
    for (; k < cnt; ++k) a1 += (float)g2[(size_t)csr[beg + k] * 19 + c];
    float s = ((a0 + a1) + (a2 + a3)) + ((a4 + a5) + (a6 + a7));
    out[(size_t)node * 19 + c] = dinv[node] * s + b2[c];
}

// ---------------- launch ----------------

extern "C" void kernel_launch(void* const* d_in, const int* in_sizes, int n_in,
                              void* d_out, int out_size, void* d_ws, size_t ws_size,
                              hipStream_t stream) {
    const float* x  = (const float*)d_in[0];
    const int*   ei = (const int*)d_in[1];
    const float* W1 = (const float*)d_in[2];
    const float* b1 = (const float*)d_in[3];
    const float* W2 = (const float*)d_in[4];
    const float* b2 = (const float*)d_in[5];
    float* out = (float*)d_out;

    int N = in_sizes[0] / 64;
    int E = in_sizes[1] / 2;
    const int* src = ei;
    const int* dst = ei + E;

    int NB = (N + BNODES - 1) >> BSH;        // 3125 for N=100000
    int NBLK = (E + EPB - 1) / EPB;          // 196 for E=1.6M

    char* w = (char*)d_ws;
    int* bcnt      = (int*)w;      w += (size_t)NB * 4;
    int* degi      = (int*)w;      w += (size_t)N * 4;
    int* node_beg  = (int*)w;      w += (size_t)N * 4;
    float* dinv    = (float*)w;    w += (size_t)N * 4;
    w = (char*)(((size_t)w + 63) & ~(size_t)63);
    // region A: hist+offs (build passes), later reused as csr (bcsr onward)
    char* regionA  = w;
    size_t histB   = (size_t)NBLK * NB * 4;                  // 2.45 MB
    size_t csrB    = (size_t)NB * CAP * 4;                   // 12.8 MB
    size_t regA    = (histB * 2 > csrB) ? histB * 2 : csrB;
    int* hist      = (int*)regionA;
    int* offs      = (int*)(regionA + histB);
    int* csr       = (int*)regionA;          // alias: hist/offs dead by k_bcsr
    w += regA;
    unsigned* ebuf = (unsigned*)w; w += (size_t)NB * CAP * 4;
    _Float16* g1   = (_Float16*)w; w += (size_t)N * 64 * 2;
    _Float16* h    = (_Float16*)w; w += (size_t)N * 64 * 2;
    _Float16* g2   = g1;  // g1 (N*64*2 B) dead after gather; reuse (N*19*2 B)

    k_hist1   <<<NBLK, TPB, 0, stream>>>(dst, hist, NB, E);
    k_scanoff <<<(NB * 8 + TPB - 1) / TPB, TPB, 0, stream>>>(hist, offs, bcnt, NBLK, NB);
    k_scatter <<<NBLK, TPB, 0, stream>>>(src, dst, offs, ebuf, NB, E);
    k_bcsr    <<<(NB + 3) / 4, TPB, 0, stream>>>(bcnt, ebuf, csr, node_beg, degi, dinv, NB, N);

    k_xw64v   <<<(N + 63) / 64, TPB, 0, stream>>>(x, W1, dinv, g1, N);
    k_gath64d <<<(N + 3) / 4, TPB, 0, stream>>>(node_beg, degi, csr, dinv, g1, b1, h, N);

    k_xw19v   <<<(N + 31) / 32, TPB, 0, stream>>>(h, W2, dinv, g2, N);
    k_gath19  <<<(N + 7) / 8, TPB, 0, stream>>>(node_beg, degi, csr, dinv, g2, b2, out, N);
}